// Round 3
// baseline (266.261 us; speedup 1.0000x reference)
//
#include <hip/hip_runtime.h>

#define BB 16
#define HIMG 64
#define WIMG 64
#define CC 256
#define NHEAD 8
#define HD 32
#define NN 4096
#define PWD 65   // 2*DH+1

__device__ __forceinline__ float elu1(float x) {
    return x > 0.0f ? x + 1.0f : __expf(x);
}
__device__ __forceinline__ float sigm(float x) {
    return 1.0f / (1.0f + __expf(-x));
}

// ---------------- Kernel 1: partial kv (K_rope^T V) and ksum -------------------
// grid = B*nch*2 (chunk x head-half), block = 256. Each block: `rows` rows x 128 ch.
__global__ __launch_bounds__(256, 8) void k1_partial(
    const float* __restrict__ x2, const float* __restrict__ x3,
    const float* __restrict__ posw, float* __restrict__ pkv,
    float* __restrict__ pksum, int nchl, int rows)
{
    const int blk   = blockIdx.x;
    const int hh    = blk & 1;                 // head-half: channels hh*128..+128
    const int bc    = blk >> 1;                // b*nch + chunk
    const int b     = bc >> nchl;
    const int chunk = bc & ((1 << nchl) - 1);
    const int n0    = chunk * rows;
    const int t     = threadIdx.x;
    const int rbase = t >> 6;                  // 0..3 (load row group)
    const int p     = t & 63;                  // slot: <32 loads k, >=32 loads v
    const int lh    = t >> 6;                  // compute: local head 0..3
    const int idx   = t & 63;
    const int dt    = idx & 7;                 // d = dt*4 .. +4
    const int et    = idx >> 3;                // e = et*4 .. +4

    __shared__ float kr_lds[8][128];
    __shared__ float v_lds[8][128];
    __shared__ float ksum_lds[4][128];

    float acc[4][4];
#pragma unroll
    for (int a = 0; a < 4; ++a)
#pragma unroll
        for (int e = 0; e < 4; ++e) acc[a][e] = 0.0f;
    float ks0 = 0.f, ks1 = 0.f, ks2 = 0.f, ks3 = 0.f;

    const float* x2b = x2 + (size_t)b * NN * CC + hh * 128;
    const float* x3b = x3 + (size_t)b * NN * CC + hh * 128;
    const float* pwb = posw + hh * 128;

    const int nstep = rows >> 3;
    for (int s = 0; s < nstep; ++s) {
        const int r0 = n0 + s * 8;
#pragma unroll
        for (int it = 0; it < 2; ++it) {
            const int row = rbase + 4 * it;    // 0..7
            const int n = r0 + row;
            if (p < 32) {
                const float4 kx = *(const float4*)(x2b + (size_t)n * CC + p * 4);
                float4 kk;
                kk.x = elu1(kx.x); kk.y = elu1(kx.y);
                kk.z = elu1(kx.z); kk.w = elu1(kx.w);
                const int ii = n >> 6, jj = n & 63;
                const float4 pv = *(const float4*)(pwb +
                    (size_t)((ii + 1) * PWD + (jj + 1)) * CC + p * 4);
                float4 kr;
                kr.x = kk.x * sigm(pv.x); kr.y = kk.y * sigm(pv.y);
                kr.z = kk.z * sigm(pv.z); kr.w = kk.w * sigm(pv.w);
                *(float4*)(&kr_lds[row][p * 4]) = kr;
                ks0 += kk.x; ks1 += kk.y; ks2 += kk.z; ks3 += kk.w;
            } else {
                const int pp = p - 32;
                const float4 vx = *(const float4*)(x3b + (size_t)n * CC + pp * 4);
                *(float4*)(&v_lds[row][pp * 4]) = vx;
            }
        }
        __syncthreads();
#pragma unroll
        for (int r = 0; r < 8; ++r) {
            const float4 k4 = *(const float4*)(&kr_lds[r][lh * 32 + dt * 4]);
            const float4 v4 = *(const float4*)(&v_lds[r][lh * 32 + et * 4]);
            const float kd[4] = {k4.x, k4.y, k4.z, k4.w};
            const float ve[4] = {v4.x, v4.y, v4.z, v4.w};
#pragma unroll
            for (int a = 0; a < 4; ++a)
#pragma unroll
                for (int e = 0; e < 4; ++e)
                    acc[a][e] = fmaf(kd[a], ve[e], acc[a][e]);
        }
        __syncthreads();
    }

    if (p < 32) {
        ksum_lds[rbase][p * 4 + 0] = ks0;
        ksum_lds[rbase][p * 4 + 1] = ks1;
        ksum_lds[rbase][p * 4 + 2] = ks2;
        ksum_lds[rbase][p * 4 + 3] = ks3;
    }
    __syncthreads();
    if (t < 128) {
        pksum[(size_t)bc * CC + hh * 128 + t] =
            ksum_lds[0][t] + ksum_lds[1][t] + ksum_lds[2][t] + ksum_lds[3][t];
    }

    // pkv layout per bc: [8 heads][32 d][32 e] — matches k2/k3 expectations
    float* dst = pkv + (size_t)bc * (NHEAD * HD * HD) + (hh * 4 + lh) * (HD * HD);
#pragma unroll
    for (int a = 0; a < 4; ++a)
#pragma unroll
        for (int e = 0; e < 4; ++e)
            dst[(dt * 4 + a) * HD + (et * 4 + e)] = acc[a][e];
}

// ---------------- Kernel 2: reduce partials, fold 1/n ---------------------------
// grid = 512, block = 256
__global__ __launch_bounds__(256) void k2_reduce(
    const float* __restrict__ pkv, const float* __restrict__ pksum,
    float* __restrict__ kvf, float* __restrict__ kmean, int nch)
{
    const int gid = blockIdx.x * 256 + threadIdx.x;   // over B*8192
    const int b = gid >> 13;
    const int o = gid & 8191;
    float s = 0.f;
#pragma unroll 4
    for (int c = 0; c < nch; ++c)
        s += pkv[(size_t)(b * nch + c) * (NHEAD * HD * HD) + o];
    kvf[gid] = s * (1.0f / NN);
    if (o < CC) {
        float ss = 0.f;
#pragma unroll 4
        for (int c = 0; c < nch; ++c)
            ss += pksum[(size_t)(b * nch + c) * CC + o];
        kmean[b * CC + o] = ss * (1.0f / NN);
    }
}

// ---------------- Kernel 3: out = q_rope@kv * z + LePE --------------------------
// grid = B*256 (quarter image row each), block = 256 (one channel each)
__global__ __launch_bounds__(256, 8) void k3_out(
    const float* __restrict__ x1, const float* __restrict__ x3,
    const float* __restrict__ posw, const float* __restrict__ kvf,
    const float* __restrict__ kmean, const float* __restrict__ lw,
    const float* __restrict__ lb, float* __restrict__ out)
{
    const int blk  = blockIdx.x;      // b*256 + irow*4 + jq
    const int b    = blk >> 8;
    const int irow = (blk >> 2) & 63;
    const int jq   = blk & 3;
    const int j0   = jq << 4;         // 0, 16, 32, 48
    const int t    = threadIdx.x;     // channel c
    const int h    = t >> 5;
    const int e    = t & 31;

    __shared__ float qr_lds[16][CC];  // 16 KiB
    __shared__ float z_lds[16][8];

    // kv column for this (h, e): kv[h][0..31][e]
    float kvc[HD];
    {
        const float* kp = kvf + (size_t)b * (NHEAD * HD * HD) + h * (HD * HD) + e;
#pragma unroll
        for (int d = 0; d < HD; ++d) kvc[d] = kp[d * HD];
    }
    float wreg[9];
#pragma unroll
    for (int q = 0; q < 9; ++q) wreg[q] = lw[t * 9 + q];
    const float bias = lb[t];

    // ---- stage: gated q quarter-row into LDS + per-pixel z ----
    {
        const int p    = t & 63;       // float4 slot within a pixel's 256 channels
        const int pixo = t >> 6;       // 0..3
        const int hh   = p >> 3;       // head of this slot
        const float4 km4 = *(const float4*)(kmean + b * CC + p * 4);
        const float* x1b = x1 + ((size_t)b * NN + (size_t)irow * 64 + j0) * CC;
        const float* pwb = posw + ((size_t)(irow + 1) * PWD + (j0 + 1)) * CC;
#pragma unroll
        for (int s = 0; s < 4; ++s) {
            const int pix = s * 4 + pixo;   // 0..15 (local)
            const float4 xv = *(const float4*)(x1b + (size_t)pix * CC + p * 4);
            float4 q4;
            q4.x = elu1(xv.x); q4.y = elu1(xv.y);
            q4.z = elu1(xv.z); q4.w = elu1(xv.w);
            const float4 pv = *(const float4*)(pwb + (size_t)pix * CC + p * 4);
            float4 qr4;
            qr4.x = q4.x * sigm(pv.x); qr4.y = q4.y * sigm(pv.y);
            qr4.z = q4.z * sigm(pv.z); qr4.w = q4.w * sigm(pv.w);
            *(float4*)(&qr_lds[pix][p * 4]) = qr4;
            float zp = q4.x * km4.x + q4.y * km4.y + q4.z * km4.z + q4.w * km4.w;
            zp += __shfl_xor(zp, 1);
            zp += __shfl_xor(zp, 2);
            zp += __shfl_xor(zp, 4);
            if ((p & 7) == 0) z_lds[pix][hh] = 1.0f / (zp + 1e-6f);
        }
    }
    __syncthreads();

    // ---- compute: tiles of 8 columns, batched independent loads for LePE ----
    const bool hasU = irow > 0, hasD = irow < 63;
    const float* rU = x3 + ((size_t)b * NN + (size_t)(irow - 1) * 64 + j0) * CC + t;
    const float* rM = x3 + ((size_t)b * NN + (size_t)irow * 64 + j0) * CC + t;
    const float* rD = x3 + ((size_t)b * NN + (size_t)(irow + 1) * 64 + j0) * CC + t;
    float* ob = out + ((size_t)b * NN + (size_t)irow * 64 + j0) * CC + t;

#pragma unroll
    for (int tt = 0; tt < 2; ++tt) {
        float cu[10], cm[10], cd[10];
#pragma unroll
        for (int q = 0; q < 10; ++q) {
            const int col = tt * 8 + q - 1;     // local col in [-1, 16]
            const int g   = j0 + col;           // global col in [-1, 64]
            const bool ok = (g >= 0) && (g < 64);
            const long off = (long)col * CC;
            cm[q] = ok ? rM[off] : 0.f;
            cu[q] = (ok && hasU) ? rU[off] : 0.f;
            cd[q] = (ok && hasD) ? rD[off] : 0.f;
        }
#pragma unroll
        for (int q = 0; q < 8; ++q) {
            const int jl = tt * 8 + q;          // local pixel 0..15
            float lepe = bias
                + wreg[0] * cu[q] + wreg[1] * cu[q + 1] + wreg[2] * cu[q + 2]
                + wreg[3] * cm[q] + wreg[4] * cm[q + 1] + wreg[5] * cm[q + 2]
                + wreg[6] * cd[q] + wreg[7] * cd[q + 1] + wreg[8] * cd[q + 2];

            float accv = 0.f;
            const float* qrow = &qr_lds[jl][h * HD];
#pragma unroll
            for (int d4 = 0; d4 < 8; ++d4) {
                const float4 qv = *(const float4*)(qrow + d4 * 4);
                accv = fmaf(qv.x, kvc[d4 * 4 + 0], accv);
                accv = fmaf(qv.y, kvc[d4 * 4 + 1], accv);
                accv = fmaf(qv.z, kvc[d4 * 4 + 2], accv);
                accv = fmaf(qv.w, kvc[d4 * 4 + 3], accv);
            }
            ob[(long)jl * CC] = accv * z_lds[jl][h] + lepe;
        }
    }
}

extern "C" void kernel_launch(void* const* d_in, const int* in_sizes, int n_in,
                              void* d_out, int out_size, void* d_ws, size_t ws_size,
                              hipStream_t stream) {
    const float* x1   = (const float*)d_in[0];
    const float* x2   = (const float*)d_in[1];
    const float* x3   = (const float*)d_in[2];
    const float* posw = (const float*)d_in[3];
    const float* lw   = (const float*)d_in[4];
    const float* lb   = (const float*)d_in[5];
    float* out = (float*)d_out;

    // choose chunking by available workspace (64 chunks needs ~35.2 MB)
    const size_t need64 = (((size_t)16 * 64 * 8192) + (size_t)16 * 64 * 256 +
                           (size_t)16 * 8192 + 16 * 256) * sizeof(float);
    const int nchl = (ws_size >= need64) ? 6 : 5;
    const int nch  = 1 << nchl;
    const int rows = NN >> nchl;

    float* pkv   = (float*)d_ws;                       // 16*nch * 8192
    float* pksum = pkv + (size_t)16 * nch * 8192;      // 16*nch * 256
    float* kvf   = pksum + (size_t)16 * nch * 256;     // 16 * 8192
    float* kmean = kvf + (size_t)16 * 8192;            // 16 * 256

    k1_partial<<<16 * nch * 2, 256, 0, stream>>>(x2, x3, posw, pkv, pksum, nchl, rows);
    k2_reduce<<<512, 256, 0, stream>>>(pkv, pksum, kvf, kmean, nch);
    k3_out<<<BB * 256, 256, 0, stream>>>(x1, x3, posw, kvf, kmean, lw, lb, out);
}

// Round 4
// 129.612 us; speedup vs baseline: 2.0543x; 2.0543x over previous
//
#include <hip/hip_runtime.h>

#define BB 16
#define HIMG 64
#define WIMG 64
#define CC 256
#define NHEAD 8
#define HD 32
#define NN 4096
#define PWD 65   // 2*DH+1

__device__ __forceinline__ float elu1(float x) {
    return x > 0.0f ? x + 1.0f : __expf(x);
}
__device__ __forceinline__ float sigm(float x) {
    return 1.0f / (1.0f + __expf(-x));
}

// ---------------- Kernel 1: partial kv (K_rope^T V) and ksum -------------------
// grid = B*nch*2 (chunk x head-half), block = 256. Each block: `rows` rows x 128 ch.
__global__ __launch_bounds__(256) void k1_partial(
    const float* __restrict__ x2, const float* __restrict__ x3,
    const float* __restrict__ posw, float* __restrict__ pkv,
    float* __restrict__ pksum, int nchl, int rows)
{
    const int blk   = blockIdx.x;
    const int hh    = blk & 1;                 // head-half: channels hh*128..+128
    const int bc    = blk >> 1;                // b*nch + chunk
    const int b     = bc >> nchl;
    const int chunk = bc & ((1 << nchl) - 1);
    const int n0    = chunk * rows;
    const int t     = threadIdx.x;
    const int rbase = t >> 6;                  // 0..3 (load row group)
    const int p     = t & 63;                  // slot: <32 loads k, >=32 loads v
    const int lh    = t >> 6;                  // compute: local head 0..3
    const int idx   = t & 63;
    const int dt    = idx & 7;                 // d = dt*4 .. +4
    const int et    = idx >> 3;                // e = et*4 .. +4

    __shared__ float kr_lds[8][128];
    __shared__ float v_lds[8][128];
    __shared__ float ksum_lds[4][128];

    float acc[4][4];
#pragma unroll
    for (int a = 0; a < 4; ++a)
#pragma unroll
        for (int e = 0; e < 4; ++e) acc[a][e] = 0.0f;
    float ks0 = 0.f, ks1 = 0.f, ks2 = 0.f, ks3 = 0.f;

    const float* x2b = x2 + (size_t)b * NN * CC + hh * 128;
    const float* x3b = x3 + (size_t)b * NN * CC + hh * 128;
    const float* pwb = posw + hh * 128;

    const int nstep = rows >> 3;
    for (int s = 0; s < nstep; ++s) {
        const int r0 = n0 + s * 8;
#pragma unroll
        for (int it = 0; it < 2; ++it) {
            const int row = rbase + 4 * it;    // 0..7
            const int n = r0 + row;
            if (p < 32) {
                const float4 kx = *(const float4*)(x2b + (size_t)n * CC + p * 4);
                float4 kk;
                kk.x = elu1(kx.x); kk.y = elu1(kx.y);
                kk.z = elu1(kx.z); kk.w = elu1(kx.w);
                const int ii = n >> 6, jj = n & 63;
                const float4 pv = *(const float4*)(pwb +
                    (size_t)((ii + 1) * PWD + (jj + 1)) * CC + p * 4);
                float4 kr;
                kr.x = kk.x * sigm(pv.x); kr.y = kk.y * sigm(pv.y);
                kr.z = kk.z * sigm(pv.z); kr.w = kk.w * sigm(pv.w);
                *(float4*)(&kr_lds[row][p * 4]) = kr;
                ks0 += kk.x; ks1 += kk.y; ks2 += kk.z; ks3 += kk.w;
            } else {
                const int pp = p - 32;
                const float4 vx = *(const float4*)(x3b + (size_t)n * CC + pp * 4);
                *(float4*)(&v_lds[row][pp * 4]) = vx;
            }
        }
        __syncthreads();
#pragma unroll
        for (int r = 0; r < 8; ++r) {
            const float4 k4 = *(const float4*)(&kr_lds[r][lh * 32 + dt * 4]);
            const float4 v4 = *(const float4*)(&v_lds[r][lh * 32 + et * 4]);
            const float kd[4] = {k4.x, k4.y, k4.z, k4.w};
            const float ve[4] = {v4.x, v4.y, v4.z, v4.w};
#pragma unroll
            for (int a = 0; a < 4; ++a)
#pragma unroll
                for (int e = 0; e < 4; ++e)
                    acc[a][e] = fmaf(kd[a], ve[e], acc[a][e]);
        }
        __syncthreads();
    }

    if (p < 32) {
        ksum_lds[rbase][p * 4 + 0] = ks0;
        ksum_lds[rbase][p * 4 + 1] = ks1;
        ksum_lds[rbase][p * 4 + 2] = ks2;
        ksum_lds[rbase][p * 4 + 3] = ks3;
    }
    __syncthreads();
    if (t < 128) {
        pksum[(size_t)bc * CC + hh * 128 + t] =
            ksum_lds[0][t] + ksum_lds[1][t] + ksum_lds[2][t] + ksum_lds[3][t];
    }

    // pkv layout per bc: [8 heads][32 d][32 e] — matches k2/k3 expectations
    float* dst = pkv + (size_t)bc * (NHEAD * HD * HD) + (hh * 4 + lh) * (HD * HD);
#pragma unroll
    for (int a = 0; a < 4; ++a)
#pragma unroll
        for (int e = 0; e < 4; ++e)
            dst[(dt * 4 + a) * HD + (et * 4 + e)] = acc[a][e];
}

// ---------------- Kernel 2: reduce partials, fold 1/n ---------------------------
// grid = 512, block = 256
__global__ __launch_bounds__(256) void k2_reduce(
    const float* __restrict__ pkv, const float* __restrict__ pksum,
    float* __restrict__ kvf, float* __restrict__ kmean, int nch)
{
    const int gid = blockIdx.x * 256 + threadIdx.x;   // over B*8192
    const int b = gid >> 13;
    const int o = gid & 8191;
    float s = 0.f;
#pragma unroll 4
    for (int c = 0; c < nch; ++c)
        s += pkv[(size_t)(b * nch + c) * (NHEAD * HD * HD) + o];
    kvf[gid] = s * (1.0f / NN);
    if (o < CC) {
        float ss = 0.f;
#pragma unroll 4
        for (int c = 0; c < nch; ++c)
            ss += pksum[(size_t)(b * nch + c) * CC + o];
        kmean[b * CC + o] = ss * (1.0f / NN);
    }
}

// ---------------- Kernel 3: out = q_rope@kv * z + LePE --------------------------
// grid = B*256 (quarter image row each), block = 256 (one channel each)
__global__ __launch_bounds__(256, 4) void k3_out(
    const float* __restrict__ x1, const float* __restrict__ x3,
    const float* __restrict__ posw, const float* __restrict__ kvf,
    const float* __restrict__ kmean, const float* __restrict__ lw,
    const float* __restrict__ lb, float* __restrict__ out)
{
    const int blk  = blockIdx.x;      // b*256 + irow*4 + jq
    const int b    = blk >> 8;
    const int irow = (blk >> 2) & 63;
    const int jq   = blk & 3;
    const int j0   = jq << 4;         // 0, 16, 32, 48
    const int t    = threadIdx.x;     // channel c
    const int h    = t >> 5;
    const int e    = t & 31;

    __shared__ float qr_lds[16][CC];  // 16 KiB
    __shared__ float z_lds[16][8];

    // kv column for this (h, e): kv[h][0..31][e]
    float kvc[HD];
    {
        const float* kp = kvf + (size_t)b * (NHEAD * HD * HD) + h * (HD * HD) + e;
#pragma unroll
        for (int d = 0; d < HD; ++d) kvc[d] = kp[d * HD];
    }
    float wreg[9];
#pragma unroll
    for (int q = 0; q < 9; ++q) wreg[q] = lw[t * 9 + q];
    const float bias = lb[t];

    // ---- stage: gated q quarter-row into LDS + per-pixel z ----
    {
        const int p    = t & 63;       // float4 slot within a pixel's 256 channels
        const int pixo = t >> 6;       // 0..3
        const int hh   = p >> 3;       // head of this slot
        const float4 km4 = *(const float4*)(kmean + b * CC + p * 4);
        const float* x1b = x1 + ((size_t)b * NN + (size_t)irow * 64 + j0) * CC;
        const float* pwb = posw + ((size_t)(irow + 1) * PWD + (j0 + 1)) * CC;
#pragma unroll
        for (int s = 0; s < 4; ++s) {
            const int pix = s * 4 + pixo;   // 0..15 (local)
            const float4 xv = *(const float4*)(x1b + (size_t)pix * CC + p * 4);
            float4 q4;
            q4.x = elu1(xv.x); q4.y = elu1(xv.y);
            q4.z = elu1(xv.z); q4.w = elu1(xv.w);
            const float4 pv = *(const float4*)(pwb + (size_t)pix * CC + p * 4);
            float4 qr4;
            qr4.x = q4.x * sigm(pv.x); qr4.y = q4.y * sigm(pv.y);
            qr4.z = q4.z * sigm(pv.z); qr4.w = q4.w * sigm(pv.w);
            *(float4*)(&qr_lds[pix][p * 4]) = qr4;
            float zp = q4.x * km4.x + q4.y * km4.y + q4.z * km4.z + q4.w * km4.w;
            zp += __shfl_xor(zp, 1);
            zp += __shfl_xor(zp, 2);
            zp += __shfl_xor(zp, 4);
            if ((p & 7) == 0) z_lds[pix][hh] = 1.0f / (zp + 1e-6f);
        }
    }
    __syncthreads();

    // ---- compute: tiles of 8 columns, batched independent loads for LePE ----
    const bool hasU = irow > 0, hasD = irow < 63;
    const float* rU = x3 + ((size_t)b * NN + (size_t)(irow - 1) * 64 + j0) * CC + t;
    const float* rM = x3 + ((size_t)b * NN + (size_t)irow * 64 + j0) * CC + t;
    const float* rD = x3 + ((size_t)b * NN + (size_t)(irow + 1) * 64 + j0) * CC + t;
    float* ob = out + ((size_t)b * NN + (size_t)irow * 64 + j0) * CC + t;

    for (int tt = 0; tt < 2; ++tt) {
        float cu[10], cm[10], cd[10];
#pragma unroll
        for (int q = 0; q < 10; ++q) {
            const int col = tt * 8 + q - 1;     // local col in [-1, 16]
            const int g   = j0 + col;           // global col in [-1, 64]
            const bool ok = (g >= 0) && (g < 64);
            const long off = (long)col * CC;
            cm[q] = ok ? rM[off] : 0.f;
            cu[q] = (ok && hasU) ? rU[off] : 0.f;
            cd[q] = (ok && hasD) ? rD[off] : 0.f;
        }
#pragma unroll
        for (int q = 0; q < 8; ++q) {
            const int jl = tt * 8 + q;          // local pixel 0..15
            float lepe = bias
                + wreg[0] * cu[q] + wreg[1] * cu[q + 1] + wreg[2] * cu[q + 2]
                + wreg[3] * cm[q] + wreg[4] * cm[q + 1] + wreg[5] * cm[q + 2]
                + wreg[6] * cd[q] + wreg[7] * cd[q + 1] + wreg[8] * cd[q + 2];

            float accv = 0.f;
            const float* qrow = &qr_lds[jl][h * HD];
#pragma unroll
            for (int d4 = 0; d4 < 8; ++d4) {
                const float4 qv = *(const float4*)(qrow + d4 * 4);
                accv = fmaf(qv.x, kvc[d4 * 4 + 0], accv);
                accv = fmaf(qv.y, kvc[d4 * 4 + 1], accv);
                accv = fmaf(qv.z, kvc[d4 * 4 + 2], accv);
                accv = fmaf(qv.w, kvc[d4 * 4 + 3], accv);
            }
            ob[(long)jl * CC] = accv * z_lds[jl][h] + lepe;
        }
    }
}

extern "C" void kernel_launch(void* const* d_in, const int* in_sizes, int n_in,
                              void* d_out, int out_size, void* d_ws, size_t ws_size,
                              hipStream_t stream) {
    const float* x1   = (const float*)d_in[0];
    const float* x2   = (const float*)d_in[1];
    const float* x3   = (const float*)d_in[2];
    const float* posw = (const float*)d_in[3];
    const float* lw   = (const float*)d_in[4];
    const float* lb   = (const float*)d_in[5];
    float* out = (float*)d_out;

    // choose chunking by available workspace (64 chunks needs ~35.2 MB)
    const size_t need64 = (((size_t)16 * 64 * 8192) + (size_t)16 * 64 * 256 +
                           (size_t)16 * 8192 + 16 * 256) * sizeof(float);
    const int nchl = (ws_size >= need64) ? 6 : 5;
    const int nch  = 1 << nchl;
    const int rows = NN >> nchl;

    float* pkv   = (float*)d_ws;                       // 16*nch * 8192
    float* pksum = pkv + (size_t)16 * nch * 8192;      // 16*nch * 256
    float* kvf   = pksum + (size_t)16 * nch * 256;     // 16 * 8192
    float* kmean = kvf + (size_t)16 * 8192;            // 16 * 256

    k1_partial<<<16 * nch * 2, 256, 0, stream>>>(x2, x3, posw, pkv, pksum, nchl, rows);
    k2_reduce<<<512, 256, 0, stream>>>(pkv, pksum, kvf, kmean, nch);
    k3_out<<<BB * 256, 256, 0, stream>>>(x1, x3, posw, kvf, kmean, lw, lb, out);
}

// Round 5
// 116.729 us; speedup vs baseline: 2.2810x; 1.1104x over previous
//
#include <hip/hip_runtime.h>

#define BB 16
#define HIMG 64
#define WIMG 64
#define CC 256
#define NHEAD 8
#define HD 32
#define NN 4096
#define PWD 65   // 2*DH+1

__device__ __forceinline__ float elu1(float x) {
    return x > 0.0f ? x + 1.0f : __expf(x);
}
__device__ __forceinline__ float sigm(float x) {
    return 1.0f / (1.0f + __expf(-x));
}

// ---------------- Kernel 1: partial kv (K_rope^T V) and ksum per chunk ----------
// grid = B * nch, block = 256. rows = NN >> nchl rows per chunk.
// Wave 0/2: k-loaders (full 1KB coalesced); wave 1/3: v-loaders. No divergence.
__global__ __launch_bounds__(256) void k1_partial(
    const float* __restrict__ x2, const float* __restrict__ x3,
    const float* __restrict__ posw, float* __restrict__ pkv,
    float* __restrict__ pksum, int nchl, int rows)
{
    const int blk   = blockIdx.x;       // b*nch + chunk
    const int b     = blk >> nchl;
    const int chunk = blk & ((1 << nchl) - 1);
    const int n0    = chunk * rows;
    const int t     = threadIdx.x;
    const int p     = t & 127;          // k-loaders: 0-63, v-loaders: 64-127
    const int rbase = t >> 7;           // 0 or 1

    const int h   = t >> 5;             // compute mapping: head
    const int idx = t & 31;
    const int dt  = idx & 7;            // d-tile (4 d's each)
    const int et  = idx >> 3;           // e-tile (8 e's each)

    __shared__ float kr_lds[8][CC];
    __shared__ float v_lds[8][CC];
    __shared__ float ksum_lds[2][CC];

    float acc[4][8];
#pragma unroll
    for (int a = 0; a < 4; ++a)
#pragma unroll
        for (int e = 0; e < 8; ++e) acc[a][e] = 0.0f;
    float ks0 = 0.f, ks1 = 0.f, ks2 = 0.f, ks3 = 0.f;

    const float* x2b = x2 + (size_t)b * NN * CC;
    const float* x3b = x3 + (size_t)b * NN * CC;

    const int nstep = rows >> 3;
    for (int s = 0; s < nstep; ++s) {
        const int r0 = n0 + s * 8;
        if (p < 64) {
            // ---- batch all 8 loads first (8 in flight) ----
            float4 kx[4], pv[4];
#pragma unroll
            for (int it = 0; it < 4; ++it) {
                const int n = r0 + rbase + 2 * it;
                kx[it] = *(const float4*)(x2b + (size_t)n * CC + p * 4);
            }
#pragma unroll
            for (int it = 0; it < 4; ++it) {
                const int n = r0 + rbase + 2 * it;
                const int ii = n >> 6, jj = n & 63;
                pv[it] = *(const float4*)(posw +
                    (size_t)((ii + 1) * PWD + (jj + 1)) * CC + p * 4);
            }
#pragma unroll
            for (int it = 0; it < 4; ++it) {
                const int row = rbase + 2 * it;
                float4 kk;
                kk.x = elu1(kx[it].x); kk.y = elu1(kx[it].y);
                kk.z = elu1(kx[it].z); kk.w = elu1(kx[it].w);
                float4 kr;
                kr.x = kk.x * sigm(pv[it].x); kr.y = kk.y * sigm(pv[it].y);
                kr.z = kk.z * sigm(pv[it].z); kr.w = kk.w * sigm(pv[it].w);
                *(float4*)(&kr_lds[row][p * 4]) = kr;
                ks0 += kk.x; ks1 += kk.y; ks2 += kk.z; ks3 += kk.w;
            }
        } else {
            const int pp = p - 64;
            float4 vx[4];
#pragma unroll
            for (int it = 0; it < 4; ++it) {
                const int n = r0 + rbase + 2 * it;
                vx[it] = *(const float4*)(x3b + (size_t)n * CC + pp * 4);
            }
#pragma unroll
            for (int it = 0; it < 4; ++it)
                *(float4*)(&v_lds[rbase + 2 * it][pp * 4]) = vx[it];
        }
        __syncthreads();
#pragma unroll
        for (int r = 0; r < 8; ++r) {
            const float4 k4 = *(const float4*)(&kr_lds[r][h * HD + dt * 4]);
            const float4 va = *(const float4*)(&v_lds[r][h * HD + et * 8]);
            const float4 vb = *(const float4*)(&v_lds[r][h * HD + et * 8 + 4]);
            const float kd[4] = {k4.x, k4.y, k4.z, k4.w};
            const float ve[8] = {va.x, va.y, va.z, va.w, vb.x, vb.y, vb.z, vb.w};
#pragma unroll
            for (int a = 0; a < 4; ++a)
#pragma unroll
                for (int e = 0; e < 8; ++e)
                    acc[a][e] = fmaf(kd[a], ve[e], acc[a][e]);
        }
        __syncthreads();
    }

    if (p < 64) {
        ksum_lds[rbase][p * 4 + 0] = ks0;
        ksum_lds[rbase][p * 4 + 1] = ks1;
        ksum_lds[rbase][p * 4 + 2] = ks2;
        ksum_lds[rbase][p * 4 + 3] = ks3;
    }
    __syncthreads();
    pksum[(size_t)blk * CC + t] = ksum_lds[0][t] + ksum_lds[1][t];

    float* dst = pkv + (size_t)blk * (NHEAD * HD * HD);
#pragma unroll
    for (int a = 0; a < 4; ++a)
#pragma unroll
        for (int e = 0; e < 8; ++e)
            dst[h * (HD * HD) + (dt * 4 + a) * HD + (et * 8 + e)] = acc[a][e];
}

// ---------------- Kernel 2: reduce partials, fold 1/n ---------------------------
// grid = 512, block = 256
__global__ __launch_bounds__(256) void k2_reduce(
    const float* __restrict__ pkv, const float* __restrict__ pksum,
    float* __restrict__ kvf, float* __restrict__ kmean, int nch)
{
    const int gid = blockIdx.x * 256 + threadIdx.x;   // over B*8192
    const int b = gid >> 13;
    const int o = gid & 8191;
    float s = 0.f;
#pragma unroll 4
    for (int c = 0; c < nch; ++c)
        s += pkv[(size_t)(b * nch + c) * (NHEAD * HD * HD) + o];
    kvf[gid] = s * (1.0f / NN);
    if (o < CC) {
        float ss = 0.f;
#pragma unroll 4
        for (int c = 0; c < nch; ++c)
            ss += pksum[(size_t)(b * nch + c) * CC + o];
        kmean[b * CC + o] = ss * (1.0f / NN);
    }
}

// ---------------- Kernel 3: out = q_rope@kv * z + LePE --------------------------
// grid = B*256 (quarter image row each), block = 256 (one channel each)
// launch_bounds(256,3): ~85 VGPR cap — room for batched loads, no spill.
__global__ __launch_bounds__(256, 3) void k3_out(
    const float* __restrict__ x1, const float* __restrict__ x3,
    const float* __restrict__ posw, const float* __restrict__ kvf,
    const float* __restrict__ kmean, const float* __restrict__ lw,
    const float* __restrict__ lb, float* __restrict__ out)
{
    const int blk  = blockIdx.x;      // b*256 + irow*4 + jq
    const int b    = blk >> 8;
    const int irow = (blk >> 2) & 63;
    const int jq   = blk & 3;
    const int j0   = jq << 4;         // 0, 16, 32, 48
    const int t    = threadIdx.x;     // channel c
    const int h    = t >> 5;
    const int e    = t & 31;

    __shared__ float qr_lds[16][CC];  // 16 KiB
    __shared__ float z_lds[16][8];

    // kv column for this (h, e): kv[h][0..31][e]
    float kvc[HD];
    {
        const float* kp = kvf + (size_t)b * (NHEAD * HD * HD) + h * (HD * HD) + e;
#pragma unroll
        for (int d = 0; d < HD; ++d) kvc[d] = kp[d * HD];
    }
    float wreg[9];
#pragma unroll
    for (int q = 0; q < 9; ++q) wreg[q] = lw[t * 9 + q];
    const float bias = lb[t];

    // ---- stage: gated q quarter-row into LDS + per-pixel z (batched loads) ----
    {
        const int p    = t & 63;       // float4 slot within a pixel's 256 channels
        const int pixo = t >> 6;       // 0..3
        const int hh   = p >> 3;       // head of this slot
        const float4 km4 = *(const float4*)(kmean + b * CC + p * 4);
        const float* x1b = x1 + ((size_t)b * NN + (size_t)irow * 64 + j0) * CC;
        const float* pwb = posw + ((size_t)(irow + 1) * PWD + (j0 + 1)) * CC;
        float4 xv[4], pvv[4];
#pragma unroll
        for (int s = 0; s < 4; ++s)
            xv[s] = *(const float4*)(x1b + (size_t)(s * 4 + pixo) * CC + p * 4);
#pragma unroll
        for (int s = 0; s < 4; ++s)
            pvv[s] = *(const float4*)(pwb + (size_t)(s * 4 + pixo) * CC + p * 4);
#pragma unroll
        for (int s = 0; s < 4; ++s) {
            const int pix = s * 4 + pixo;   // 0..15 (local)
            float4 q4;
            q4.x = elu1(xv[s].x); q4.y = elu1(xv[s].y);
            q4.z = elu1(xv[s].z); q4.w = elu1(xv[s].w);
            float4 qr4;
            qr4.x = q4.x * sigm(pvv[s].x); qr4.y = q4.y * sigm(pvv[s].y);
            qr4.z = q4.z * sigm(pvv[s].z); qr4.w = q4.w * sigm(pvv[s].w);
            *(float4*)(&qr_lds[pix][p * 4]) = qr4;
            float zp = q4.x * km4.x + q4.y * km4.y + q4.z * km4.z + q4.w * km4.w;
            zp += __shfl_xor(zp, 1);
            zp += __shfl_xor(zp, 2);
            zp += __shfl_xor(zp, 4);
            if ((p & 7) == 0) z_lds[pix][hh] = 1.0f / (zp + 1e-6f);
        }
    }
    __syncthreads();

    // ---- compute: 2 tiles of 8 columns; lepe row-by-row, then matvec ----
    const bool hasU = irow > 0, hasD = irow < 63;
    const float* rU = x3 + ((size_t)b * NN + (size_t)(irow - 1) * 64 + j0) * CC + t;
    const float* rM = x3 + ((size_t)b * NN + (size_t)irow * 64 + j0) * CC + t;
    const float* rD = x3 + ((size_t)b * NN + (size_t)(irow + 1) * 64 + j0) * CC + t;
    float* ob = out + ((size_t)b * NN + (size_t)irow * 64 + j0) * CC + t;

    for (int tt = 0; tt < 2; ++tt) {
        float lep[8];
#pragma unroll
        for (int q = 0; q < 8; ++q) lep[q] = bias;
        // mid row
        {
            float cm[10];
#pragma unroll
            for (int q = 0; q < 10; ++q) {
                const int col = tt * 8 + q - 1;
                const int g   = j0 + col;
                cm[q] = (g >= 0 && g < 64) ? rM[(long)col * CC] : 0.f;
            }
#pragma unroll
            for (int q = 0; q < 8; ++q)
                lep[q] += wreg[3] * cm[q] + wreg[4] * cm[q + 1] + wreg[5] * cm[q + 2];
        }
        // upper row
        {
            float cu[10];
#pragma unroll
            for (int q = 0; q < 10; ++q) {
                const int col = tt * 8 + q - 1;
                const int g   = j0 + col;
                cu[q] = (g >= 0 && g < 64 && hasU) ? rU[(long)col * CC] : 0.f;
            }
#pragma unroll
            for (int q = 0; q < 8; ++q)
                lep[q] += wreg[0] * cu[q] + wreg[1] * cu[q + 1] + wreg[2] * cu[q + 2];
        }
        // lower row
        {
            float cd[10];
#pragma unroll
            for (int q = 0; q < 10; ++q) {
                const int col = tt * 8 + q - 1;
                const int g   = j0 + col;
                cd[q] = (g >= 0 && g < 64 && hasD) ? rD[(long)col * CC] : 0.f;
            }
#pragma unroll
            for (int q = 0; q < 8; ++q)
                lep[q] += wreg[6] * cd[q] + wreg[7] * cd[q + 1] + wreg[8] * cd[q + 2];
        }
        // matvec: 2 independent accumulators
#pragma unroll
        for (int q = 0; q < 8; ++q) {
            const int jl = tt * 8 + q;          // local pixel 0..15
            const float* qrow = &qr_lds[jl][h * HD];
            float a0 = 0.f, a1 = 0.f;
#pragma unroll
            for (int d4 = 0; d4 < 4; ++d4) {
                const float4 qa = *(const float4*)(qrow + d4 * 4);
                const float4 qb = *(const float4*)(qrow + 16 + d4 * 4);
                a0 = fmaf(qa.x, kvc[d4 * 4 + 0], a0);
                a0 = fmaf(qa.y, kvc[d4 * 4 + 1], a0);
                a0 = fmaf(qa.z, kvc[d4 * 4 + 2], a0);
                a0 = fmaf(qa.w, kvc[d4 * 4 + 3], a0);
                a1 = fmaf(qb.x, kvc[16 + d4 * 4 + 0], a1);
                a1 = fmaf(qb.y, kvc[16 + d4 * 4 + 1], a1);
                a1 = fmaf(qb.z, kvc[16 + d4 * 4 + 2], a1);
                a1 = fmaf(qb.w, kvc[16 + d4 * 4 + 3], a1);
            }
            ob[(long)jl * CC] = (a0 + a1) * z_lds[jl][h] + lep[q];
        }
    }
}

extern "C" void kernel_launch(void* const* d_in, const int* in_sizes, int n_in,
                              void* d_out, int out_size, void* d_ws, size_t ws_size,
                              hipStream_t stream) {
    const float* x1   = (const float*)d_in[0];
    const float* x2   = (const float*)d_in[1];
    const float* x3   = (const float*)d_in[2];
    const float* posw = (const float*)d_in[3];
    const float* lw   = (const float*)d_in[4];
    const float* lb   = (const float*)d_in[5];
    float* out = (float*)d_out;

    // choose chunking by available workspace (64 chunks needs ~35.2 MB)
    const size_t need64 = (((size_t)16 * 64 * 8192) + (size_t)16 * 64 * 256 +
                           (size_t)16 * 8192 + 16 * 256) * sizeof(float);
    const int nchl = (ws_size >= need64) ? 6 : 5;
    const int nch  = 1 << nchl;
    const int rows = NN >> nchl;

    float* pkv   = (float*)d_ws;                       // 16*nch * 8192
    float* pksum = pkv + (size_t)16 * nch * 8192;      // 16*nch * 256
    float* kvf   = pksum + (size_t)16 * nch * 256;     // 16 * 8192
    float* kmean = kvf + (size_t)16 * 8192;            // 16 * 256

    k1_partial<<<16 * nch, 256, 0, stream>>>(x2, x3, posw, pkv, pksum, nchl, rows);
    k2_reduce<<<512, 256, 0, stream>>>(pkv, pksum, kvf, kmean, nch);
    k3_out<<<BB * 256, 256, 0, stream>>>(x1, x3, posw, kvf, kmean, lw, lb, out);
}

// Round 6
// 102.150 us; speedup vs baseline: 2.6066x; 1.1427x over previous
//
#include <hip/hip_runtime.h>

#define BB 16
#define HIMG 64
#define WIMG 64
#define CC 256
#define NHEAD 8
#define HD 32
#define NN 4096
#define PWD 65   // 2*DH+1

__device__ __forceinline__ float elu1(float x) {
    return x > 0.0f ? x + 1.0f : __expf(x);
}
__device__ __forceinline__ float sigm(float x) {
    return 1.0f / (1.0f + __expf(-x));
}

// ---------------- Kernel 0: pw[n][c] = sigmoid(posw[i+1][j+1][c]) ---------------
// grid = 1024, block = 256 (one float4 per thread over 4096*64 slots)
__global__ __launch_bounds__(256) void k0_pw(
    const float* __restrict__ posw, float* __restrict__ pw)
{
    const int gid = blockIdx.x * 256 + threadIdx.x;  // 0 .. 262143
    const int n = gid >> 6;        // pixel 0..4095
    const int p = gid & 63;        // float4 slot
    const int ii = n >> 6, jj = n & 63;
    const float4 v = *(const float4*)(posw + (size_t)((ii + 1) * PWD + (jj + 1)) * CC + p * 4);
    float4 r;
    r.x = sigm(v.x); r.y = sigm(v.y); r.z = sigm(v.z); r.w = sigm(v.w);
    *(float4*)(pw + (size_t)n * CC + p * 4) = r;
}

// ---------------- Kernel 1: partial kv (K_rope^T V) and ksum per chunk ----------
// grid = B * nch, block = 256. Double-buffered 4-row steps, one barrier/step.
__global__ __launch_bounds__(256) void k1_partial(
    const float* __restrict__ x2, const float* __restrict__ x3,
    const float* __restrict__ pw, float* __restrict__ pkv,
    float* __restrict__ pksum, int nchl, int rows)
{
    const int blk   = blockIdx.x;       // b*nch + chunk
    const int b     = blk >> nchl;
    const int chunk = blk & ((1 << nchl) - 1);
    const int n0    = chunk * rows;
    const int t     = threadIdx.x;
    const int p     = t & 127;          // k-loaders: 0-63, v-loaders: 64-127
    const int pp    = p - 64;
    const int rbase = t >> 7;           // 0 or 1

    const int h   = t >> 5;             // compute mapping: head
    const int idx = t & 31;
    const int dt  = idx & 7;            // d-tile (4 d's each)
    const int et  = idx >> 3;           // e-tile (8 e's each)

    __shared__ float kr_lds[2][4][CC];
    __shared__ float v_lds[2][4][CC];
    __shared__ float ksum_lds[2][CC];

    float acc[4][8];
#pragma unroll
    for (int a = 0; a < 4; ++a)
#pragma unroll
        for (int e = 0; e < 8; ++e) acc[a][e] = 0.0f;
    float ks0 = 0.f, ks1 = 0.f, ks2 = 0.f, ks3 = 0.f;

    const float* x2b = x2 + (size_t)b * NN * CC;
    const float* x3b = x3 + (size_t)b * NN * CC;

    const int nstep = rows >> 2;        // 4 rows per step
    float4 kx[2], pv[2], vx[2];

    // prologue: issue loads for step 0
    {
        const int r0 = n0;
        if (p < 64) {
#pragma unroll
            for (int it = 0; it < 2; ++it) {
                const int n = r0 + rbase + 2 * it;
                kx[it] = *(const float4*)(x2b + (size_t)n * CC + p * 4);
            }
#pragma unroll
            for (int it = 0; it < 2; ++it) {
                const int n = r0 + rbase + 2 * it;
                pv[it] = *(const float4*)(pw + (size_t)n * CC + p * 4);
            }
        } else {
#pragma unroll
            for (int it = 0; it < 2; ++it) {
                const int n = r0 + rbase + 2 * it;
                vx[it] = *(const float4*)(x3b + (size_t)n * CC + pp * 4);
            }
        }
    }

    int buf = 0;
    for (int s = 0; s < nstep; ++s) {
        // ---- write current regs to LDS[buf] ----
        if (p < 64) {
#pragma unroll
            for (int it = 0; it < 2; ++it) {
                const int row = rbase + 2 * it;
                float4 kk;
                kk.x = elu1(kx[it].x); kk.y = elu1(kx[it].y);
                kk.z = elu1(kx[it].z); kk.w = elu1(kx[it].w);
                float4 kr;
                kr.x = kk.x * pv[it].x; kr.y = kk.y * pv[it].y;
                kr.z = kk.z * pv[it].z; kr.w = kk.w * pv[it].w;
                *(float4*)(&kr_lds[buf][row][p * 4]) = kr;
                ks0 += kk.x; ks1 += kk.y; ks2 += kk.z; ks3 += kk.w;
            }
        } else {
#pragma unroll
            for (int it = 0; it < 2; ++it)
                *(float4*)(&v_lds[buf][rbase + 2 * it][pp * 4]) = vx[it];
        }
        __syncthreads();
        // ---- issue loads for step s+1 (overlap with compute below) ----
        if (s + 1 < nstep) {
            const int r0 = n0 + (s + 1) * 4;
            if (p < 64) {
#pragma unroll
                for (int it = 0; it < 2; ++it) {
                    const int n = r0 + rbase + 2 * it;
                    kx[it] = *(const float4*)(x2b + (size_t)n * CC + p * 4);
                }
#pragma unroll
                for (int it = 0; it < 2; ++it) {
                    const int n = r0 + rbase + 2 * it;
                    pv[it] = *(const float4*)(pw + (size_t)n * CC + p * 4);
                }
            } else {
#pragma unroll
                for (int it = 0; it < 2; ++it) {
                    const int n = r0 + rbase + 2 * it;
                    vx[it] = *(const float4*)(x3b + (size_t)n * CC + pp * 4);
                }
            }
        }
        // ---- compute from LDS[buf] ----
#pragma unroll
        for (int r = 0; r < 4; ++r) {
            const float4 k4 = *(const float4*)(&kr_lds[buf][r][h * HD + dt * 4]);
            const float4 va = *(const float4*)(&v_lds[buf][r][h * HD + et * 8]);
            const float4 vb = *(const float4*)(&v_lds[buf][r][h * HD + et * 8 + 4]);
            const float kd[4] = {k4.x, k4.y, k4.z, k4.w};
            const float ve[8] = {va.x, va.y, va.z, va.w, vb.x, vb.y, vb.z, vb.w};
#pragma unroll
            for (int a = 0; a < 4; ++a)
#pragma unroll
                for (int e = 0; e < 8; ++e)
                    acc[a][e] = fmaf(kd[a], ve[e], acc[a][e]);
        }
        buf ^= 1;
    }

    if (p < 64) {
        ksum_lds[rbase][p * 4 + 0] = ks0;
        ksum_lds[rbase][p * 4 + 1] = ks1;
        ksum_lds[rbase][p * 4 + 2] = ks2;
        ksum_lds[rbase][p * 4 + 3] = ks3;
    }
    __syncthreads();
    pksum[(size_t)blk * CC + t] = ksum_lds[0][t] + ksum_lds[1][t];

    float* dst = pkv + (size_t)blk * (NHEAD * HD * HD);
#pragma unroll
    for (int a = 0; a < 4; ++a)
#pragma unroll
        for (int e = 0; e < 8; ++e)
            dst[h * (HD * HD) + (dt * 4 + a) * HD + (et * 8 + e)] = acc[a][e];
}

// ---------------- Kernel 2: reduce partials, fold 1/n ---------------------------
// grid = 512, block = 256
__global__ __launch_bounds__(256) void k2_reduce(
    const float* __restrict__ pkv, const float* __restrict__ pksum,
    float* __restrict__ kvf, float* __restrict__ kmean, int nch)
{
    const int gid = blockIdx.x * 256 + threadIdx.x;   // over B*8192
    const int b = gid >> 13;
    const int o = gid & 8191;
    float s = 0.f;
#pragma unroll 4
    for (int c = 0; c < nch; ++c)
        s += pkv[(size_t)(b * nch + c) * (NHEAD * HD * HD) + o];
    kvf[gid] = s * (1.0f / NN);
    if (o < CC) {
        float ss = 0.f;
#pragma unroll 4
        for (int c = 0; c < nch; ++c)
            ss += pksum[(size_t)(b * nch + c) * CC + o];
        kmean[b * CC + o] = ss * (1.0f / NN);
    }
}

// ---------------- Kernel 3: out = q_rope@kv * z + LePE --------------------------
// grid = B*256 (quarter image row each), block = 256 (one channel each)
__global__ __launch_bounds__(256) void k3_out(
    const float* __restrict__ x1, const float* __restrict__ x3,
    const float* __restrict__ pw, const float* __restrict__ kvf,
    const float* __restrict__ kmean, const float* __restrict__ lw,
    const float* __restrict__ lb, float* __restrict__ out)
{
    const int blk  = blockIdx.x;      // b*256 + irow*4 + jq
    const int b    = blk >> 8;
    const int irow = (blk >> 2) & 63;
    const int jq   = blk & 3;
    const int j0   = jq << 4;         // 0, 16, 32, 48
    const int t    = threadIdx.x;     // channel c
    const int h    = t >> 5;
    const int e    = t & 31;

    __shared__ float qr_lds[16][CC];  // 16 KiB
    __shared__ float z_lds[16][8];

    // kv column for this (h, e): kv[h][0..31][e]
    float kvc[HD];
    {
        const float* kp = kvf + (size_t)b * (NHEAD * HD * HD) + h * (HD * HD) + e;
#pragma unroll
        for (int d = 0; d < HD; ++d) kvc[d] = kp[d * HD];
    }
    float wreg[9];
#pragma unroll
    for (int q = 0; q < 9; ++q) wreg[q] = lw[t * 9 + q];
    const float bias = lb[t];

    // ---- stage: gated q quarter-row into LDS + per-pixel z (batched loads) ----
    {
        const int p    = t & 63;       // float4 slot within a pixel's 256 channels
        const int pixo = t >> 6;       // 0..3
        const int hh   = p >> 3;       // head of this slot
        const float4 km4 = *(const float4*)(kmean + b * CC + p * 4);
        const float* x1b = x1 + ((size_t)b * NN + (size_t)irow * 64 + j0) * CC;
        const float* pwb = pw + ((size_t)irow * 64 + j0) * CC;
        float4 xv[4], pvv[4];
#pragma unroll
        for (int s = 0; s < 4; ++s)
            xv[s] = *(const float4*)(x1b + (size_t)(s * 4 + pixo) * CC + p * 4);
#pragma unroll
        for (int s = 0; s < 4; ++s)
            pvv[s] = *(const float4*)(pwb + (size_t)(s * 4 + pixo) * CC + p * 4);
#pragma unroll
        for (int s = 0; s < 4; ++s) {
            const int pix = s * 4 + pixo;   // 0..15 (local)
            float4 q4;
            q4.x = elu1(xv[s].x); q4.y = elu1(xv[s].y);
            q4.z = elu1(xv[s].z); q4.w = elu1(xv[s].w);
            float4 qr4;
            qr4.x = q4.x * pvv[s].x; qr4.y = q4.y * pvv[s].y;
            qr4.z = q4.z * pvv[s].z; qr4.w = q4.w * pvv[s].w;
            *(float4*)(&qr_lds[pix][p * 4]) = qr4;
            float zp = q4.x * km4.x + q4.y * km4.y + q4.z * km4.z + q4.w * km4.w;
            zp += __shfl_xor(zp, 1);
            zp += __shfl_xor(zp, 2);
            zp += __shfl_xor(zp, 4);
            if ((p & 7) == 0) z_lds[pix][hh] = 1.0f / (zp + 1e-6f);
        }
    }
    __syncthreads();

    // ---- compute: 2 tiles of 8 columns; merged halo batch, lepe, matvec ----
    const bool hasU = irow > 0, hasD = irow < 63;
    const float* rU = x3 + ((size_t)b * NN + (size_t)(irow - 1) * 64 + j0) * CC + t;
    const float* rM = x3 + ((size_t)b * NN + (size_t)irow * 64 + j0) * CC + t;
    const float* rD = x3 + ((size_t)b * NN + (size_t)(irow + 1) * 64 + j0) * CC + t;
    float* ob = out + ((size_t)b * NN + (size_t)irow * 64 + j0) * CC + t;

    for (int tt = 0; tt < 2; ++tt) {
        float cu[10], cm[10], cd[10];
#pragma unroll
        for (int q = 0; q < 10; ++q) {
            const int col = tt * 8 + q - 1;     // local col in [-1, 16]
            const int g   = j0 + col;           // global col in [-1, 64]
            const bool ok = (g >= 0) && (g < 64);
            const long off = (long)col * CC;
            cm[q] = ok ? rM[off] : 0.f;
            cu[q] = (ok && hasU) ? rU[off] : 0.f;
            cd[q] = (ok && hasD) ? rD[off] : 0.f;
        }
#pragma unroll
        for (int q = 0; q < 8; ++q) {
            const int jl = tt * 8 + q;          // local pixel 0..15
            float lepe = bias
                + wreg[0] * cu[q] + wreg[1] * cu[q + 1] + wreg[2] * cu[q + 2]
                + wreg[3] * cm[q] + wreg[4] * cm[q + 1] + wreg[5] * cm[q + 2]
                + wreg[6] * cd[q] + wreg[7] * cd[q + 1] + wreg[8] * cd[q + 2];

            const float* qrow = &qr_lds[jl][h * HD];
            float a0 = 0.f, a1 = 0.f;
#pragma unroll
            for (int d4 = 0; d4 < 4; ++d4) {
                const float4 qa = *(const float4*)(qrow + d4 * 4);
                const float4 qb = *(const float4*)(qrow + 16 + d4 * 4);
                a0 = fmaf(qa.x, kvc[d4 * 4 + 0], a0);
                a0 = fmaf(qa.y, kvc[d4 * 4 + 1], a0);
                a0 = fmaf(qa.z, kvc[d4 * 4 + 2], a0);
                a0 = fmaf(qa.w, kvc[d4 * 4 + 3], a0);
                a1 = fmaf(qb.x, kvc[16 + d4 * 4 + 0], a1);
                a1 = fmaf(qb.y, kvc[16 + d4 * 4 + 1], a1);
                a1 = fmaf(qb.z, kvc[16 + d4 * 4 + 2], a1);
                a1 = fmaf(qb.w, kvc[16 + d4 * 4 + 3], a1);
            }
            __builtin_nontemporal_store((a0 + a1) * z_lds[jl][h] + lepe,
                                        ob + (long)jl * CC);
        }
    }
}

extern "C" void kernel_launch(void* const* d_in, const int* in_sizes, int n_in,
                              void* d_out, int out_size, void* d_ws, size_t ws_size,
                              hipStream_t stream) {
    const float* x1   = (const float*)d_in[0];
    const float* x2   = (const float*)d_in[1];
    const float* x3   = (const float*)d_in[2];
    const float* posw = (const float*)d_in[3];
    const float* lw   = (const float*)d_in[4];
    const float* lb   = (const float*)d_in[5];
    float* out = (float*)d_out;

    // ws layout: pw | pkv | pksum | kvf | kmean
    const size_t pw_sz = (size_t)NN * CC;                       // 4 MB
    const size_t need64 = (pw_sz + (size_t)16 * 64 * 8192 + (size_t)16 * 64 * 256 +
                           (size_t)16 * 8192 + 16 * 256) * sizeof(float);
    const int nchl = (ws_size >= need64) ? 6 : 5;
    const int nch  = 1 << nchl;
    const int rows = NN >> nchl;

    float* pwb   = (float*)d_ws;
    float* pkv   = pwb + pw_sz;                        // 16*nch * 8192
    float* pksum = pkv + (size_t)16 * nch * 8192;      // 16*nch * 256
    float* kvf   = pksum + (size_t)16 * nch * 256;     // 16 * 8192
    float* kmean = kvf + (size_t)16 * 8192;            // 16 * 256

    k0_pw<<<1024, 256, 0, stream>>>(posw, pwb);
    k1_partial<<<16 * nch, 256, 0, stream>>>(x2, x3, pwb, pkv, pksum, nchl, rows);
    k2_reduce<<<512, 256, 0, stream>>>(pkv, pksum, kvf, kmean, nch);
    k3_out<<<BB * 256, 256, 0, stream>>>(x1, x3, pwb, kvf, kmean, lw, lb, out);
}

// Round 7
// 102.095 us; speedup vs baseline: 2.6080x; 1.0005x over previous
//
#include <hip/hip_runtime.h>

#define BB 16
#define HIMG 64
#define WIMG 64
#define CC 256
#define NHEAD 8
#define HD 32
#define NN 4096
#define PWD 65   // 2*DH+1

__device__ __forceinline__ float elu1(float x) {
    return x > 0.0f ? x + 1.0f : __expf(x);
}
__device__ __forceinline__ float sigm(float x) {
    return 1.0f / (1.0f + __expf(-x));
}

// ---------------- Kernel 0: pw[n][c] = sigmoid(posw[i+1][j+1][c]) ---------------
// grid = 1024, block = 256 (one float4 per thread over 4096*64 slots)
__global__ __launch_bounds__(256) void k0_pw(
    const float* __restrict__ posw, float* __restrict__ pw)
{
    const int gid = blockIdx.x * 256 + threadIdx.x;  // 0 .. 262143
    const int n = gid >> 6;        // pixel 0..4095
    const int p = gid & 63;        // float4 slot
    const int ii = n >> 6, jj = n & 63;
    const float4 v = *(const float4*)(posw + (size_t)((ii + 1) * PWD + (jj + 1)) * CC + p * 4);
    float4 r;
    r.x = sigm(v.x); r.y = sigm(v.y); r.z = sigm(v.z); r.w = sigm(v.w);
    *(float4*)(pw + (size_t)n * CC + p * 4) = r;
}

// ---------------- Kernel 1: partial kv (K_rope^T V) and ksum per chunk ----------
// grid = B * nch, block = 256. Double-buffered 4-row steps, one barrier/step.
__global__ __launch_bounds__(256) void k1_partial(
    const float* __restrict__ x2, const float* __restrict__ x3,
    const float* __restrict__ pw, float* __restrict__ pkv,
    float* __restrict__ pksum, int nchl, int rows)
{
    const int blk   = blockIdx.x;       // b*nch + chunk
    const int b     = blk >> nchl;
    const int chunk = blk & ((1 << nchl) - 1);
    const int n0    = chunk * rows;
    const int t     = threadIdx.x;
    const int p     = t & 127;          // k-loaders: 0-63, v-loaders: 64-127
    const int pp    = p - 64;
    const int rbase = t >> 7;           // 0 or 1

    const int h   = t >> 5;             // compute mapping: head
    const int idx = t & 31;
    const int dt  = idx & 7;            // d-tile (4 d's each)
    const int et  = idx >> 3;           // e-tile (8 e's each)

    __shared__ float kr_lds[2][4][CC];
    __shared__ float v_lds[2][4][CC];
    __shared__ float ksum_lds[2][CC];

    float acc[4][8];
#pragma unroll
    for (int a = 0; a < 4; ++a)
#pragma unroll
        for (int e = 0; e < 8; ++e) acc[a][e] = 0.0f;
    float ks0 = 0.f, ks1 = 0.f, ks2 = 0.f, ks3 = 0.f;

    const float* x2b = x2 + (size_t)b * NN * CC;
    const float* x3b = x3 + (size_t)b * NN * CC;

    const int nstep = rows >> 2;        // 4 rows per step
    float4 kx[2], pv[2], vx[2];

    // prologue: issue loads for step 0
    {
        const int r0 = n0;
        if (p < 64) {
#pragma unroll
            for (int it = 0; it < 2; ++it) {
                const int n = r0 + rbase + 2 * it;
                kx[it] = *(const float4*)(x2b + (size_t)n * CC + p * 4);
            }
#pragma unroll
            for (int it = 0; it < 2; ++it) {
                const int n = r0 + rbase + 2 * it;
                pv[it] = *(const float4*)(pw + (size_t)n * CC + p * 4);
            }
        } else {
#pragma unroll
            for (int it = 0; it < 2; ++it) {
                const int n = r0 + rbase + 2 * it;
                vx[it] = *(const float4*)(x3b + (size_t)n * CC + pp * 4);
            }
        }
    }

    int buf = 0;
    for (int s = 0; s < nstep; ++s) {
        // ---- write current regs to LDS[buf] ----
        if (p < 64) {
#pragma unroll
            for (int it = 0; it < 2; ++it) {
                const int row = rbase + 2 * it;
                float4 kk;
                kk.x = elu1(kx[it].x); kk.y = elu1(kx[it].y);
                kk.z = elu1(kx[it].z); kk.w = elu1(kx[it].w);
                float4 kr;
                kr.x = kk.x * pv[it].x; kr.y = kk.y * pv[it].y;
                kr.z = kk.z * pv[it].z; kr.w = kk.w * pv[it].w;
                *(float4*)(&kr_lds[buf][row][p * 4]) = kr;
                ks0 += kk.x; ks1 += kk.y; ks2 += kk.z; ks3 += kk.w;
            }
        } else {
#pragma unroll
            for (int it = 0; it < 2; ++it)
                *(float4*)(&v_lds[buf][rbase + 2 * it][pp * 4]) = vx[it];
        }
        __syncthreads();
        // ---- issue loads for step s+1 (overlap with compute below) ----
        if (s + 1 < nstep) {
            const int r0 = n0 + (s + 1) * 4;
            if (p < 64) {
#pragma unroll
                for (int it = 0; it < 2; ++it) {
                    const int n = r0 + rbase + 2 * it;
                    kx[it] = *(const float4*)(x2b + (size_t)n * CC + p * 4);
                }
#pragma unroll
                for (int it = 0; it < 2; ++it) {
                    const int n = r0 + rbase + 2 * it;
                    pv[it] = *(const float4*)(pw + (size_t)n * CC + p * 4);
                }
            } else {
#pragma unroll
                for (int it = 0; it < 2; ++it) {
                    const int n = r0 + rbase + 2 * it;
                    vx[it] = *(const float4*)(x3b + (size_t)n * CC + pp * 4);
                }
            }
        }
        // ---- compute from LDS[buf] ----
#pragma unroll
        for (int r = 0; r < 4; ++r) {
            const float4 k4 = *(const float4*)(&kr_lds[buf][r][h * HD + dt * 4]);
            const float4 va = *(const float4*)(&v_lds[buf][r][h * HD + et * 8]);
            const float4 vb = *(const float4*)(&v_lds[buf][r][h * HD + et * 8 + 4]);
            const float kd[4] = {k4.x, k4.y, k4.z, k4.w};
            const float ve[8] = {va.x, va.y, va.z, va.w, vb.x, vb.y, vb.z, vb.w};
#pragma unroll
            for (int a = 0; a < 4; ++a)
#pragma unroll
                for (int e = 0; e < 8; ++e)
                    acc[a][e] = fmaf(kd[a], ve[e], acc[a][e]);
        }
        buf ^= 1;
    }

    if (p < 64) {
        ksum_lds[rbase][p * 4 + 0] = ks0;
        ksum_lds[rbase][p * 4 + 1] = ks1;
        ksum_lds[rbase][p * 4 + 2] = ks2;
        ksum_lds[rbase][p * 4 + 3] = ks3;
    }
    __syncthreads();
    pksum[(size_t)blk * CC + t] = ksum_lds[0][t] + ksum_lds[1][t];

    float* dst = pkv + (size_t)blk * (NHEAD * HD * HD);
#pragma unroll
    for (int a = 0; a < 4; ++a)
#pragma unroll
        for (int e = 0; e < 8; ++e)
            dst[h * (HD * HD) + (dt * 4 + a) * HD + (et * 8 + e)] = acc[a][e];
}

// ---------------- Kernel 2: reduce partials, fold 1/n ---------------------------
// grid = 512, block = 256
__global__ __launch_bounds__(256) void k2_reduce(
    const float* __restrict__ pkv, const float* __restrict__ pksum,
    float* __restrict__ kvf, float* __restrict__ kmean, int nch)
{
    const int gid = blockIdx.x * 256 + threadIdx.x;   // over B*8192
    const int b = gid >> 13;
    const int o = gid & 8191;
    float s = 0.f;
#pragma unroll 4
    for (int c = 0; c < nch; ++c)
        s += pkv[(size_t)(b * nch + c) * (NHEAD * HD * HD) + o];
    kvf[gid] = s * (1.0f / NN);
    if (o < CC) {
        float ss = 0.f;
#pragma unroll 4
        for (int c = 0; c < nch; ++c)
            ss += pksum[(size_t)(b * nch + c) * CC + o];
        kmean[b * CC + o] = ss * (1.0f / NN);
    }
}

// ---------------- Kernel 3: out = q_rope@kv * z + LePE --------------------------
// grid = B*256 (quarter image row each), block = 256 (one channel each)
// launch_bounds(256,3): ~168 VGPR budget — hold BOTH tiles' 60 halo loads in
// flight (deep MLP) at the occupancy we actually achieve anyway (12 waves/CU).
__global__ __launch_bounds__(256, 3) void k3_out(
    const float* __restrict__ x1, const float* __restrict__ x3,
    const float* __restrict__ pw, const float* __restrict__ kvf,
    const float* __restrict__ kmean, const float* __restrict__ lw,
    const float* __restrict__ lb, float* __restrict__ out)
{
    const int blk  = blockIdx.x;      // b*256 + irow*4 + jq
    const int b    = blk >> 8;
    const int irow = (blk >> 2) & 63;
    const int jq   = blk & 3;
    const int j0   = jq << 4;         // 0, 16, 32, 48
    const int t    = threadIdx.x;     // channel c
    const int h    = t >> 5;
    const int e    = t & 31;

    __shared__ float qr_lds[16][CC];  // 16 KiB
    __shared__ float z_lds[16][8];

    // kv column for this (h, e): kv[h][0..31][e]
    float kvc[HD];
    {
        const float* kp = kvf + (size_t)b * (NHEAD * HD * HD) + h * (HD * HD) + e;
#pragma unroll
        for (int d = 0; d < HD; ++d) kvc[d] = kp[d * HD];
    }
    float wreg[9];
#pragma unroll
    for (int q = 0; q < 9; ++q) wreg[q] = lw[t * 9 + q];
    const float bias = lb[t];

    // ---- stage: gated q quarter-row into LDS + per-pixel z (batched loads) ----
    {
        const int p    = t & 63;       // float4 slot within a pixel's 256 channels
        const int pixo = t >> 6;       // 0..3
        const int hh   = p >> 3;       // head of this slot
        const float4 km4 = *(const float4*)(kmean + b * CC + p * 4);
        const float* x1b = x1 + ((size_t)b * NN + (size_t)irow * 64 + j0) * CC;
        const float* pwb = pw + ((size_t)irow * 64 + j0) * CC;
        float4 xv[4], pvv[4];
#pragma unroll
        for (int s = 0; s < 4; ++s)
            xv[s] = *(const float4*)(x1b + (size_t)(s * 4 + pixo) * CC + p * 4);
#pragma unroll
        for (int s = 0; s < 4; ++s)
            pvv[s] = *(const float4*)(pwb + (size_t)(s * 4 + pixo) * CC + p * 4);
#pragma unroll
        for (int s = 0; s < 4; ++s) {
            const int pix = s * 4 + pixo;   // 0..15 (local)
            float4 q4;
            q4.x = elu1(xv[s].x); q4.y = elu1(xv[s].y);
            q4.z = elu1(xv[s].z); q4.w = elu1(xv[s].w);
            float4 qr4;
            qr4.x = q4.x * pvv[s].x; qr4.y = q4.y * pvv[s].y;
            qr4.z = q4.z * pvv[s].z; qr4.w = q4.w * pvv[s].w;
            *(float4*)(&qr_lds[pix][p * 4]) = qr4;
            float zp = q4.x * km4.x + q4.y * km4.y + q4.z * km4.z + q4.w * km4.w;
            zp += __shfl_xor(zp, 1);
            zp += __shfl_xor(zp, 2);
            zp += __shfl_xor(zp, 4);
            if ((p & 7) == 0) z_lds[pix][hh] = 1.0f / (zp + 1e-6f);
        }
    }
    __syncthreads();

    // ---- compute: load ALL 60 halo values first (both tiles), then compute ----
    const bool hasU = irow > 0, hasD = irow < 63;
    const float* rU = x3 + ((size_t)b * NN + (size_t)(irow - 1) * 64 + j0) * CC + t;
    const float* rM = x3 + ((size_t)b * NN + (size_t)irow * 64 + j0) * CC + t;
    const float* rD = x3 + ((size_t)b * NN + (size_t)(irow + 1) * 64 + j0) * CC + t;
    float* ob = out + ((size_t)b * NN + (size_t)irow * 64 + j0) * CC + t;

    float cu[2][10], cm[2][10], cd[2][10];
#pragma unroll
    for (int tt = 0; tt < 2; ++tt)
#pragma unroll
        for (int q = 0; q < 10; ++q) {
            const int col = tt * 8 + q - 1;     // local col in [-1, 16]
            const int g   = j0 + col;           // global col in [-1, 64]
            const bool ok = (g >= 0) && (g < 64);
            const long off = (long)col * CC;
            cm[tt][q] = ok ? rM[off] : 0.f;
            cu[tt][q] = (ok && hasU) ? rU[off] : 0.f;
            cd[tt][q] = (ok && hasD) ? rD[off] : 0.f;
        }

#pragma unroll
    for (int tt = 0; tt < 2; ++tt) {
#pragma unroll
        for (int q = 0; q < 8; ++q) {
            const int jl = tt * 8 + q;          // local pixel 0..15
            float lepe = bias
                + wreg[0] * cu[tt][q] + wreg[1] * cu[tt][q + 1] + wreg[2] * cu[tt][q + 2]
                + wreg[3] * cm[tt][q] + wreg[4] * cm[tt][q + 1] + wreg[5] * cm[tt][q + 2]
                + wreg[6] * cd[tt][q] + wreg[7] * cd[tt][q + 1] + wreg[8] * cd[tt][q + 2];

            const float* qrow = &qr_lds[jl][h * HD];
            float a0 = 0.f, a1 = 0.f;
#pragma unroll
            for (int d4 = 0; d4 < 4; ++d4) {
                const float4 qa = *(const float4*)(qrow + d4 * 4);
                const float4 qb = *(const float4*)(qrow + 16 + d4 * 4);
                a0 = fmaf(qa.x, kvc[d4 * 4 + 0], a0);
                a0 = fmaf(qa.y, kvc[d4 * 4 + 1], a0);
                a0 = fmaf(qa.z, kvc[d4 * 4 + 2], a0);
                a0 = fmaf(qa.w, kvc[d4 * 4 + 3], a0);
                a1 = fmaf(qb.x, kvc[16 + d4 * 4 + 0], a1);
                a1 = fmaf(qb.y, kvc[16 + d4 * 4 + 1], a1);
                a1 = fmaf(qb.z, kvc[16 + d4 * 4 + 2], a1);
                a1 = fmaf(qb.w, kvc[16 + d4 * 4 + 3], a1);
            }
            __builtin_nontemporal_store((a0 + a1) * z_lds[jl][h] + lepe,
                                        ob + (long)jl * CC);
        }
    }
}

extern "C" void kernel_launch(void* const* d_in, const int* in_sizes, int n_in,
                              void* d_out, int out_size, void* d_ws, size_t ws_size,
                              hipStream_t stream) {
    const float* x1   = (const float*)d_in[0];
    const float* x2   = (const float*)d_in[1];
    const float* x3   = (const float*)d_in[2];
    const float* posw = (const float*)d_in[3];
    const float* lw   = (const float*)d_in[4];
    const float* lb   = (const float*)d_in[5];
    float* out = (float*)d_out;

    // ws layout: pw | pkv | pksum | kvf | kmean
    const size_t pw_sz = (size_t)NN * CC;                       // 4 MB
    const size_t need64 = (pw_sz + (size_t)16 * 64 * 8192 + (size_t)16 * 64 * 256 +
                           (size_t)16 * 8192 + 16 * 256) * sizeof(float);
    const int nchl = (ws_size >= need64) ? 6 : 5;
    const int nch  = 1 << nchl;
    const int rows = NN >> nchl;

    float* pwb   = (float*)d_ws;
    float* pkv   = pwb + pw_sz;                        // 16*nch * 8192
    float* pksum = pkv + (size_t)16 * nch * 8192;      // 16*nch * 256
    float* kvf   = pksum + (size_t)16 * nch * 256;     // 16 * 8192
    float* kmean = kvf + (size_t)16 * 8192;            // 16 * 256

    k0_pw<<<1024, 256, 0, stream>>>(posw, pwb);
    k1_partial<<<16 * nch, 256, 0, stream>>>(x2, x3, pwb, pkv, pksum, nchl, rows);
    k2_reduce<<<512, 256, 0, stream>>>(pkv, pksum, kvf, kmean, nch);
    k3_out<<<BB * 256, 256, 0, stream>>>(x1, x3, pwb, kvf, kmean, lw, lb, out);
}

// Round 8
// 100.695 us; speedup vs baseline: 2.6442x; 1.0139x over previous
//
#include <hip/hip_runtime.h>

#define BB 16
#define HIMG 64
#define WIMG 64
#define CC 256
#define NHEAD 8
#define HD 32
#define NN 4096
#define PWD 65   // 2*DH+1
#define PADC 264 // qr_bf row stride (ushorts): 528B row = 2-way-free LDS banking

typedef short bf16x8 __attribute__((ext_vector_type(8)));
typedef float f32x4 __attribute__((ext_vector_type(4)));

__device__ __forceinline__ float elu1(float x) {
    return x > 0.0f ? x + 1.0f : __expf(x);
}
__device__ __forceinline__ float sigm(float x) {
    return 1.0f / (1.0f + __expf(-x));
}
__device__ __forceinline__ unsigned short f2bf(float f) {
    union { float f; unsigned int u; } v; v.f = f;
    unsigned int r = v.u + 0x7FFFu + ((v.u >> 16) & 1u);   // RNE
    return (unsigned short)(r >> 16);
}

// ---------------- Kernel 0: pw[n][c] = sigmoid(posw[i+1][j+1][c]) ---------------
__global__ __launch_bounds__(256) void k0_pw(
    const float* __restrict__ posw, float* __restrict__ pw)
{
    const int gid = blockIdx.x * 256 + threadIdx.x;  // 0 .. 262143
    const int n = gid >> 6;
    const int p = gid & 63;
    const int ii = n >> 6, jj = n & 63;
    const float4 v = *(const float4*)(posw + (size_t)((ii + 1) * PWD + (jj + 1)) * CC + p * 4);
    float4 r;
    r.x = sigm(v.x); r.y = sigm(v.y); r.z = sigm(v.z); r.w = sigm(v.w);
    *(float4*)(pw + (size_t)n * CC + p * 4) = r;
}

// ---------------- Kernel 1: partial kv (K_rope^T V) and ksum per chunk ----------
// grid = B * nch, block = 256. Double-buffered 4-row steps, one barrier/step.
__global__ __launch_bounds__(256) void k1_partial(
    const float* __restrict__ x2, const float* __restrict__ x3,
    const float* __restrict__ pw, float* __restrict__ pkv,
    float* __restrict__ pksum, int nchl, int rows)
{
    const int blk   = blockIdx.x;
    const int b     = blk >> nchl;
    const int chunk = blk & ((1 << nchl) - 1);
    const int n0    = chunk * rows;
    const int t     = threadIdx.x;
    const int p     = t & 127;
    const int pp    = p - 64;
    const int rbase = t >> 7;

    const int h   = t >> 5;
    const int idx = t & 31;
    const int dt  = idx & 7;
    const int et  = idx >> 3;

    __shared__ float kr_lds[2][4][CC];
    __shared__ float v_lds[2][4][CC];
    __shared__ float ksum_lds[2][CC];

    float acc[4][8];
#pragma unroll
    for (int a = 0; a < 4; ++a)
#pragma unroll
        for (int e = 0; e < 8; ++e) acc[a][e] = 0.0f;
    float ks0 = 0.f, ks1 = 0.f, ks2 = 0.f, ks3 = 0.f;

    const float* x2b = x2 + (size_t)b * NN * CC;
    const float* x3b = x3 + (size_t)b * NN * CC;

    const int nstep = rows >> 2;
    float4 kx[2], pv[2], vx[2];

    {
        const int r0 = n0;
        if (p < 64) {
#pragma unroll
            for (int it = 0; it < 2; ++it) {
                const int n = r0 + rbase + 2 * it;
                kx[it] = *(const float4*)(x2b + (size_t)n * CC + p * 4);
            }
#pragma unroll
            for (int it = 0; it < 2; ++it) {
                const int n = r0 + rbase + 2 * it;
                pv[it] = *(const float4*)(pw + (size_t)n * CC + p * 4);
            }
        } else {
#pragma unroll
            for (int it = 0; it < 2; ++it) {
                const int n = r0 + rbase + 2 * it;
                vx[it] = *(const float4*)(x3b + (size_t)n * CC + pp * 4);
            }
        }
    }

    int buf = 0;
    for (int s = 0; s < nstep; ++s) {
        if (p < 64) {
#pragma unroll
            for (int it = 0; it < 2; ++it) {
                const int row = rbase + 2 * it;
                float4 kk;
                kk.x = elu1(kx[it].x); kk.y = elu1(kx[it].y);
                kk.z = elu1(kx[it].z); kk.w = elu1(kx[it].w);
                float4 kr;
                kr.x = kk.x * pv[it].x; kr.y = kk.y * pv[it].y;
                kr.z = kk.z * pv[it].z; kr.w = kk.w * pv[it].w;
                *(float4*)(&kr_lds[buf][row][p * 4]) = kr;
                ks0 += kk.x; ks1 += kk.y; ks2 += kk.z; ks3 += kk.w;
            }
        } else {
#pragma unroll
            for (int it = 0; it < 2; ++it)
                *(float4*)(&v_lds[buf][rbase + 2 * it][pp * 4]) = vx[it];
        }
        __syncthreads();
        if (s + 1 < nstep) {
            const int r0 = n0 + (s + 1) * 4;
            if (p < 64) {
#pragma unroll
                for (int it = 0; it < 2; ++it) {
                    const int n = r0 + rbase + 2 * it;
                    kx[it] = *(const float4*)(x2b + (size_t)n * CC + p * 4);
                }
#pragma unroll
                for (int it = 0; it < 2; ++it) {
                    const int n = r0 + rbase + 2 * it;
                    pv[it] = *(const float4*)(pw + (size_t)n * CC + p * 4);
                }
            } else {
#pragma unroll
                for (int it = 0; it < 2; ++it) {
                    const int n = r0 + rbase + 2 * it;
                    vx[it] = *(const float4*)(x3b + (size_t)n * CC + pp * 4);
                }
            }
        }
#pragma unroll
        for (int r = 0; r < 4; ++r) {
            const float4 k4 = *(const float4*)(&kr_lds[buf][r][h * HD + dt * 4]);
            const float4 va = *(const float4*)(&v_lds[buf][r][h * HD + et * 8]);
            const float4 vb = *(const float4*)(&v_lds[buf][r][h * HD + et * 8 + 4]);
            const float kd[4] = {k4.x, k4.y, k4.z, k4.w};
            const float ve[8] = {va.x, va.y, va.z, va.w, vb.x, vb.y, vb.z, vb.w};
#pragma unroll
            for (int a = 0; a < 4; ++a)
#pragma unroll
                for (int e = 0; e < 8; ++e)
                    acc[a][e] = fmaf(kd[a], ve[e], acc[a][e]);
        }
        buf ^= 1;
    }

    if (p < 64) {
        ksum_lds[rbase][p * 4 + 0] = ks0;
        ksum_lds[rbase][p * 4 + 1] = ks1;
        ksum_lds[rbase][p * 4 + 2] = ks2;
        ksum_lds[rbase][p * 4 + 3] = ks3;
    }
    __syncthreads();
    pksum[(size_t)blk * CC + t] = ksum_lds[0][t] + ksum_lds[1][t];

    float* dst = pkv + (size_t)blk * (NHEAD * HD * HD);
#pragma unroll
    for (int a = 0; a < 4; ++a)
#pragma unroll
        for (int e = 0; e < 8; ++e)
            dst[h * (HD * HD) + (dt * 4 + a) * HD + (et * 8 + e)] = acc[a][e];
}

// ---------------- Kernel 2: reduce partials; emit kvbT (bf16, [b][h][e][d]) -----
// grid = 512, block = 256
__global__ __launch_bounds__(256) void k2_reduce(
    const float* __restrict__ pkv, const float* __restrict__ pksum,
    unsigned short* __restrict__ kvbT, float* __restrict__ kmean, int nch)
{
    const int gid = blockIdx.x * 256 + threadIdx.x;   // over B*8192
    const int b = gid >> 13;
    const int o = gid & 8191;
    float s = 0.f;
#pragma unroll 4
    for (int c = 0; c < nch; ++c)
        s += pkv[(size_t)(b * nch + c) * (NHEAD * HD * HD) + o];
    const int hh = o >> 10, d = (o >> 5) & 31, e = o & 31;
    kvbT[(((size_t)b * NHEAD + hh) * HD + e) * HD + d] = f2bf(s * (1.0f / NN));
    if (o < CC) {
        float ss = 0.f;
#pragma unroll 4
        for (int c = 0; c < nch; ++c)
            ss += pksum[(size_t)(b * nch + c) * CC + o];
        kmean[b * CC + o] = ss * (1.0f / NN);
    }
}

// ---------------- Kernel 3: out = MFMA((qr*z) @ kv) + LePE ----------------------
// grid = B*256 (quarter image row each), block = 256 (4 waves)
__global__ __launch_bounds__(256, 2) void k3_out(
    const float* __restrict__ x1, const float* __restrict__ x3,
    const float* __restrict__ pw, const unsigned short* __restrict__ kvbT,
    const float* __restrict__ kmean, const float* __restrict__ lw,
    const float* __restrict__ lb, float* __restrict__ out)
{
    const int blk  = blockIdx.x;      // b*256 + irow*4 + jq
    const int b    = blk >> 8;
    const int irow = (blk >> 2) & 63;
    const int jq   = blk & 3;
    const int j0   = jq << 4;         // 0, 16, 32, 48
    const int t    = threadIdx.x;

    __shared__ unsigned short qr_bf[16 * PADC];   // (qr * z) in bf16, 8.4 KiB
    __shared__ float attn_lds[16][CC];            // 16 KiB

    float wreg[9];
#pragma unroll
    for (int q = 0; q < 9; ++q) wreg[q] = lw[t * 9 + q];
    const float bias = lb[t];

    // ---- stage: q_rope * z  -> bf16 LDS (z folded in; known after shfl reduce) ----
    {
        const int p    = t & 63;       // float4 slot within a pixel's 256 channels
        const int pixo = t >> 6;       // 0..3
        const float4 km4 = *(const float4*)(kmean + b * CC + p * 4);
        const float* x1b = x1 + ((size_t)b * NN + (size_t)irow * 64 + j0) * CC;
        const float* pwb = pw + ((size_t)irow * 64 + j0) * CC;
        float4 xv[4], pvv[4];
#pragma unroll
        for (int s = 0; s < 4; ++s)
            xv[s] = *(const float4*)(x1b + (size_t)(s * 4 + pixo) * CC + p * 4);
#pragma unroll
        for (int s = 0; s < 4; ++s)
            pvv[s] = *(const float4*)(pwb + (size_t)(s * 4 + pixo) * CC + p * 4);
#pragma unroll
        for (int s = 0; s < 4; ++s) {
            const int pix = s * 4 + pixo;   // 0..15 (local)
            float4 q4;
            q4.x = elu1(xv[s].x); q4.y = elu1(xv[s].y);
            q4.z = elu1(xv[s].z); q4.w = elu1(xv[s].w);
            float zp = q4.x * km4.x + q4.y * km4.y + q4.z * km4.z + q4.w * km4.w;
            zp += __shfl_xor(zp, 1);
            zp += __shfl_xor(zp, 2);
            zp += __shfl_xor(zp, 4);        // all 8 lanes of this head have the sum
            const float zin = 1.0f / (zp + 1e-6f);
            ushort4 u;
            u.x = f2bf(q4.x * pvv[s].x * zin);
            u.y = f2bf(q4.y * pvv[s].y * zin);
            u.z = f2bf(q4.z * pvv[s].z * zin);
            u.w = f2bf(q4.w * pvv[s].w * zin);
            *(ushort4*)(&qr_bf[pix * PADC + p * 4]) = u;
        }
    }

    // ---- halo loads issued BEFORE the barrier: cannot be sunk past it ----
    const bool hasU = irow > 0, hasD = irow < 63;
    const float* rU = x3 + ((size_t)b * NN + (size_t)(irow - 1) * 64 + j0) * CC + t;
    const float* rM = x3 + ((size_t)b * NN + (size_t)irow * 64 + j0) * CC + t;
    const float* rD = x3 + ((size_t)b * NN + (size_t)(irow + 1) * 64 + j0) * CC + t;

    float cu[2][10], cm[2][10], cd[2][10];
#pragma unroll
    for (int tt = 0; tt < 2; ++tt)
#pragma unroll
        for (int q = 0; q < 10; ++q) {
            const int col = tt * 8 + q - 1;     // local col in [-1, 16]
            const int g   = j0 + col;           // global col in [-1, 64]
            const bool ok = (g >= 0) && (g < 64);
            const long off = (long)col * CC;
            cm[tt][q] = ok ? rM[off] : 0.f;
            cu[tt][q] = (ok && hasU) ? rU[off] : 0.f;
            cd[tt][q] = (ok && hasD) ? rD[off] : 0.f;
        }

    __syncthreads();

    // ---- MFMA phase: wave w covers heads 2w,2w+1 over all 16 pixels ----
    {
        const int w  = t >> 6;
        const int l  = t & 63;
        const int lr = l & 15;     // A row (pixel) / B col / D col
        const int lg = l >> 4;     // k-group

        bf16x8 af0 = *(const bf16x8*)(&qr_bf[lr * PADC + (w * 2 + 0) * HD + lg * 8]);
        bf16x8 af1 = *(const bf16x8*)(&qr_bf[lr * PADC + (w * 2 + 1) * HD + lg * 8]);

        f32x4 acc[4];
#pragma unroll
        for (int ct = 0; ct < 4; ++ct) {
            const int head = w * 2 + (ct >> 1);
            const int cl   = (ct & 1) * 16 + lr;
            const bf16x8 bf = *(const bf16x8*)(kvbT +
                (((size_t)b * NHEAD + head) * HD + cl) * HD + lg * 8);
            f32x4 z4 = {0.f, 0.f, 0.f, 0.f};
            acc[ct] = __builtin_amdgcn_mfma_f32_16x16x32_bf16(
                (ct < 2) ? af0 : af1, bf, z4, 0, 0, 0);
        }
#pragma unroll
        for (int ct = 0; ct < 4; ++ct) {
            const int c = (w * 2 + (ct >> 1)) * HD + (ct & 1) * 16 + lr;
#pragma unroll
            for (int r = 0; r < 4; ++r)
                attn_lds[lg * 4 + r][c] = acc[ct][r];
        }
    }

    __syncthreads();

    // ---- epilogue: lepe (registers already loaded) + attn + store ----
    float* ob = out + ((size_t)b * NN + (size_t)irow * 64 + j0) * CC + t;
#pragma unroll
    for (int tt = 0; tt < 2; ++tt) {
#pragma unroll
        for (int q = 0; q < 8; ++q) {
            const int jl = tt * 8 + q;          // local pixel 0..15
            float lepe = bias
                + wreg[0] * cu[tt][q] + wreg[1] * cu[tt][q + 1] + wreg[2] * cu[tt][q + 2]
                + wreg[3] * cm[tt][q] + wreg[4] * cm[tt][q + 1] + wreg[5] * cm[tt][q + 2]
                + wreg[6] * cd[tt][q] + wreg[7] * cd[tt][q + 1] + wreg[8] * cd[tt][q + 2];
            __builtin_nontemporal_store(attn_lds[jl][t] + lepe, ob + (long)jl * CC);
        }
    }
}

extern "C" void kernel_launch(void* const* d_in, const int* in_sizes, int n_in,
                              void* d_out, int out_size, void* d_ws, size_t ws_size,
                              hipStream_t stream) {
    const float* x1   = (const float*)d_in[0];
    const float* x2   = (const float*)d_in[1];
    const float* x3   = (const float*)d_in[2];
    const float* posw = (const float*)d_in[3];
    const float* lw   = (const float*)d_in[4];
    const float* lb   = (const float*)d_in[5];
    float* out = (float*)d_out;

    // ws layout: pw | pkv | pksum | kmean | kvbT(ushort)
    const size_t pw_sz = (size_t)NN * CC;                       // 1M floats
    const size_t need64 = (pw_sz + (size_t)16 * 64 * 8192 + (size_t)16 * 64 * 256 +
                           (size_t)16 * 256) * sizeof(float) +
                          (size_t)16 * 8192 * sizeof(unsigned short);
    const int nchl = (ws_size >= need64) ? 6 : 5;
    const int nch  = 1 << nchl;
    const int rows = NN >> nchl;

    float* pwb   = (float*)d_ws;
    float* pkv   = pwb + pw_sz;                        // 16*nch * 8192
    float* pksum = pkv + (size_t)16 * nch * 8192;      // 16*nch * 256
    float* kmean = pksum + (size_t)16 * nch * 256;     // 16 * 256
    unsigned short* kvbT = (unsigned short*)(kmean + (size_t)16 * 256);  // 16*8192

    k0_pw<<<1024, 256, 0, stream>>>(posw, pwb);
    k1_partial<<<16 * nch, 256, 0, stream>>>(x2, x3, pwb, pkv, pksum, nchl, rows);
    k2_reduce<<<512, 256, 0, stream>>>(pkv, pksum, kvbT, kmean, nch);
    k3_out<<<BB * 256, 256, 0, stream>>>(x1, x3, pwb, kvbT, kmean, lw, lb, out);
}